// Round 4
// baseline (622.616 us; speedup 1.0000x reference)
//
#include <hip/hip_runtime.h>
#include <hip/hip_bf16.h>
#include <cmath>

typedef __hip_bfloat16 bf16;
typedef __attribute__((ext_vector_type(8))) short s16x8;
typedef __attribute__((ext_vector_type(4))) float f32x4;

#define B_  8
#define C_  384
#define NQ  4096
#define NK  1024
#define NH  8
#define HD  48
#define F_  1536

__device__ __forceinline__ float bits2f(short s) {
    unsigned int u = ((unsigned int)(unsigned short)s) << 16;
    float f; __builtin_memcpy(&f, &u, 4); return f;
}
__device__ __forceinline__ short f2bits(float f) {
    bf16 h = __float2bfloat16(f);
    short s; __builtin_memcpy(&s, &h, 2); return s;
}

// async global->LDS, 16 B per lane; l must be wave-uniform (HW adds lane*16)
__device__ __forceinline__ void gload16(const bf16* g, bf16* l) {
    __builtin_amdgcn_global_load_lds(
        (const __attribute__((address_space(1))) void*)g,
        (__attribute__((address_space(3))) void*)l, 16, 0, 0);
}

// ---------------------------------------------------------------------------
// GRN step 1: gx[b*C+c] = sqrt(sum over spatial of x^2). One block per (b,c).
// ---------------------------------------------------------------------------
__global__ __launch_bounds__(256)
void grn_gx(const float* __restrict__ x, float* __restrict__ gx, int nsp)
{
    size_t base = (size_t)blockIdx.x * nsp;
    float s = 0.0f;
    for (int i = threadIdx.x * 4; i < nsp; i += 256 * 4) {
        float4 v = *reinterpret_cast<const float4*>(&x[base + i]);
        s += v.x * v.x + v.y * v.y + v.z * v.z + v.w * v.w;
    }
    for (int m = 32; m; m >>= 1) s += __shfl_xor(s, m);
    __shared__ float sh[4];
    if ((threadIdx.x & 63) == 0) sh[threadIdx.x >> 6] = s;
    __syncthreads();
    if (threadIdx.x == 0) gx[blockIdx.x] = sqrtf(sh[0] + sh[1] + sh[2] + sh[3]);
}

// ---------------------------------------------------------------------------
// GRN step 2: scale[b*C+c] = (1+gamma[c]) * gx/(mean_c(gx)+eps) + 1
// ---------------------------------------------------------------------------
__global__ __launch_bounds__(384)
void grn_scale(const float* __restrict__ gx, const float* __restrict__ gamma,
               float* __restrict__ scale)
{
    int b = blockIdx.x;
    int c = threadIdx.x;            // 384 threads
    float g = gx[b * C_ + c];
    float s = g;
    for (int m = 32; m; m >>= 1) s += __shfl_xor(s, m);
    __shared__ float sh[6];
    if ((c & 63) == 0) sh[c >> 6] = s;
    __syncthreads();
    if (c == 0) {
        float t = 0.0f;
        for (int i = 0; i < 6; ++i) t += sh[i];
        sh[0] = t / (float)C_;
    }
    __syncthreads();
    float nx = g / (sh[0] + 1e-6f);
    scale[b * C_ + c] = (1.0f + gamma[c]) * nx + 1.0f;
}

// ---------------------------------------------------------------------------
// fp32 -> bf16 convert (weights). n multiple of 2048.
// ---------------------------------------------------------------------------
__global__ __launch_bounds__(256)
void cvt_bf16(const float* __restrict__ src, bf16* __restrict__ dst, int n)
{
    int i = (blockIdx.x * 256 + threadIdx.x) * 8;
    if (i >= n) return;
    float4 a = *reinterpret_cast<const float4*>(src + i);
    float4 b = *reinterpret_cast<const float4*>(src + i + 4);
    s16x8 o;
    o[0] = f2bits(a.x); o[1] = f2bits(a.y); o[2] = f2bits(a.z); o[3] = f2bits(a.w);
    o[4] = f2bits(b.x); o[5] = f2bits(b.y); o[6] = f2bits(b.z); o[7] = f2bits(b.w);
    *reinterpret_cast<s16x8*>(dst + i) = o;
}

// ---------------------------------------------------------------------------
// Transpose channel-major fp32 [b][c][m] -> token-major bf16 [b][m][c],
// optional fused affine (GRN): v*scale[b,c] + shift[c]. 64x64 tiles.
// ---------------------------------------------------------------------------
template<bool SCALED>
__global__ __launch_bounds__(256)
void t2b(const float* __restrict__ src, bf16* __restrict__ dst,
         const float* __restrict__ scale, const float* __restrict__ shift, int Msp)
{
    const int b = blockIdx.z, c0 = blockIdx.y * 64, m0 = blockIdx.x * 64;
    __shared__ float T[64][65];
    const int tr = threadIdx.x >> 6, tc = threadIdx.x & 63;
    const float* sp = src + ((size_t)b * C_ + c0) * Msp + m0;
#pragma unroll
    for (int i = 0; i < 16; ++i)
        T[i * 4 + tr][tc] = sp[(size_t)(i * 4 + tr) * Msp + tc];
    __syncthreads();
    const int c = c0 + tc;
    float scl = 1.0f, sh = 0.0f;
    if constexpr (SCALED) { scl = scale[b * C_ + c]; sh = shift[c]; }
    bf16* dp = dst + ((size_t)b * Msp + m0) * C_ + c;
#pragma unroll
    for (int i = 0; i < 16; ++i) {
        int m = i * 4 + tr;
        dp[(size_t)m * C_] = __float2bfloat16(T[tc][m] * scl + sh);
    }
}

// ---------------------------------------------------------------------------
// MFMA GEMM (m97 structure): out[m][n] = sum_k A[m][k]*W[n][k], bf16 inputs.
// 128x128 tile, BK=32, 4 waves (2x2), 4x4 16x16x32 frags per wave.
// Staging via global_load_lds width=16 into LINEAR LDS [128][32] (64 B rows).
// Per K-step: 4 gload/wave, 2 barriers, 16 MFMA/wave.
// EPI: 0 = bf16 token-major (+bias), 1 = +silu, bf16 token-major,
//      2 = channel-major fp32: outF = query + val*sc1
//      3 = channel-major fp32: outF = query + (outF + val*sc1)*sc2
// ---------------------------------------------------------------------------
template<int EPI>
__global__ __launch_bounds__(256)
void gemm_mfma(const bf16* __restrict__ A, const bf16* __restrict__ W,
               const float* __restrict__ bias, int N, int K, int Mspat,
               bf16* __restrict__ outB, float* __restrict__ outF,
               const float* __restrict__ query,
               const float* __restrict__ sc1, const float* __restrict__ sc2)
{
    __shared__ __align__(16) char smem_raw[33792];
    bf16* As = (bf16*)smem_raw;          // [128][32] linear
    bf16* Bs = As + 128 * 32;            // [128][32] linear
    const int tid  = threadIdx.x;
    const int lane = tid & 63, wave = tid >> 6;
    const int wm = wave >> 1, wn = wave & 1;
    const int lrow = lane & 15, lk8 = lane >> 4;
    const int mrow0 = blockIdx.x * 128;
    const int nt    = blockIdx.y * 128;

    // staging geometry: wave w covers rows [w*32, w*32+32) of each tile,
    // 2 instructions of 16 rows; lane l -> row r0+(l>>2), k-slot (l&3)*8.
    const int r0   = wave * 32;               // uniform per wave
    const int srow = r0 + (lane >> 2);        // per-lane global row
    const int sk   = (lane & 3) * 8;          // per-lane k offset
    const bf16* Ag = A + (size_t)(mrow0 + srow) * K + sk;
    const bf16* Wg = W + (size_t)(nt    + srow) * K + sk;
    bf16* AsD = As + r0 * 32;                 // uniform LDS bases
    bf16* BsD = Bs + r0 * 32;
    f32x4 acc[4][4] = {};

    for (int kt = 0; kt < K; kt += 32) {
        __syncthreads();                      // prior frag reads complete
        gload16(Ag + kt,               AsD);
        gload16(Ag + kt + (size_t)16 * K, AsD + 16 * 32);
        gload16(Wg + kt,               BsD);
        gload16(Wg + kt + (size_t)16 * K, BsD + 16 * 32);
        __syncthreads();                      // staged tile visible
        s16x8 af[4], bfr[4];
#pragma unroll
        for (int m = 0; m < 4; ++m)
            af[m] = *reinterpret_cast<const s16x8*>(As + (wm * 64 + m * 16 + lrow) * 32 + lk8 * 8);
#pragma unroll
        for (int n = 0; n < 4; ++n)
            bfr[n] = *reinterpret_cast<const s16x8*>(Bs + (wn * 64 + n * 16 + lrow) * 32 + lk8 * 8);
#pragma unroll
        for (int m = 0; m < 4; ++m)
#pragma unroll
            for (int n = 0; n < 4; ++n)
                acc[m][n] = __builtin_amdgcn_mfma_f32_16x16x32_bf16(af[m], bfr[n], acc[m][n], 0, 0, 0);
    }
    __syncthreads();   // all frag reads done before smem reuse

    if constexpr (EPI <= 1) {
        bf16* Cs = (bf16*)smem_raw;      // [128][128]
#pragma unroll
        for (int m = 0; m < 4; ++m)
#pragma unroll
            for (int n = 0; n < 4; ++n) {
                int col = wn * 64 + n * 16 + lrow;
                float bv = bias[nt + col];
#pragma unroll
                for (int j = 0; j < 4; ++j) {
                    int row = wm * 64 + m * 16 + lk8 * 4 + j;
                    float v = acc[m][n][j] + bv;
                    if constexpr (EPI == 1) v = v / (1.0f + __expf(-v));
                    Cs[row * 128 + col] = __float2bfloat16(v);
                }
            }
        __syncthreads();
#pragma unroll
        for (int p = 0; p < 8; ++p) {
            int e = p * 256 + tid;
            int row = e >> 4, ch = (e & 15) * 8;
            *reinterpret_cast<s16x8*>(outB + (size_t)(mrow0 + row) * N + nt + ch) =
                *reinterpret_cast<const s16x8*>(Cs + row * 128 + ch);
        }
    } else {
        float* Cs2 = (float*)smem_raw;   // [64][132] fp32
        const int b = mrow0 / Mspat;
        const int mloc0 = mrow0 - b * Mspat;
        for (int half = 0; half < 2; ++half) {
            if (half) __syncthreads();
            if (wn == half) {
#pragma unroll
                for (int m = 0; m < 4; ++m)
#pragma unroll
                    for (int n = 0; n < 4; ++n) {
                        int crow = n * 16 + lrow;
                        float bv = bias[nt + half * 64 + crow];
#pragma unroll
                        for (int j = 0; j < 4; ++j) {
                            int mcol = wm * 64 + m * 16 + lk8 * 4 + j;
                            Cs2[crow * 132 + mcol] = acc[m][n][j] + bv;
                        }
                    }
            }
            __syncthreads();
#pragma unroll
            for (int p = 0; p < 8; ++p) {
                int e = p * 256 + tid;
                int crow = e >> 5, m4 = (e & 31) * 4;
                int c = nt + half * 64 + crow;
                size_t off = ((size_t)b * C_ + c) * Mspat + mloc0 + m4;
                float4 v  = *reinterpret_cast<const float4*>(Cs2 + crow * 132 + m4);
                float4 q4 = *reinterpret_cast<const float4*>(query + off);
                float s1 = sc1[c];
                float4 o;
                if constexpr (EPI == 2) {
                    o.x = q4.x + v.x * s1;
                    o.y = q4.y + v.y * s1;
                    o.z = q4.z + v.z * s1;
                    o.w = q4.w + v.w * s1;
                } else {
                    float4 w4 = *reinterpret_cast<const float4*>(outF + off);
                    float s2 = sc2[c];
                    o.x = q4.x + (w4.x + v.x * s1) * s2;
                    o.y = q4.y + (w4.y + v.y * s1) * s2;
                    o.z = q4.z + (w4.z + v.z * s1) * s2;
                    o.w = q4.w + (w4.w + v.w * s1) * s2;
                }
                *reinterpret_cast<float4*>(outF + off) = o;
            }
        }
    }
}

// ---------------------------------------------------------------------------
// LayerNorm(384) + elu+1 over bf16 token-major rows, in place. 1 wave/row.
// ---------------------------------------------------------------------------
__global__ __launch_bounds__(256)
void ln_elu_b(bf16* __restrict__ x, const float* __restrict__ w,
              const float* __restrict__ bb)
{
    int lane = threadIdx.x & 63, wid = threadIdx.x >> 6;
    int row = blockIdx.x * 4 + wid;
    bf16* p = x + (size_t)row * C_;
    float v[6];
#pragma unroll
    for (int i = 0; i < 6; ++i) v[i] = __bfloat162float(p[lane + i * 64]);
    float s = 0.0f;
#pragma unroll
    for (int i = 0; i < 6; ++i) s += v[i];
    for (int m = 32; m; m >>= 1) s += __shfl_xor(s, m);
    float mu = s / (float)C_;
    float vs = 0.0f;
#pragma unroll
    for (int i = 0; i < 6; ++i) { float d = v[i] - mu; vs += d * d; }
    for (int m = 32; m; m >>= 1) vs += __shfl_xor(vs, m);
    float inv = rsqrtf(vs / (float)C_ + 1e-5f);
#pragma unroll
    for (int i = 0; i < 6; ++i) {
        int c = lane + i * 64;
        float y = (v[i] - mu) * inv * w[c] + bb[c];
        p[c] = __float2bfloat16((y > 0.0f) ? (y + 1.0f) : __expf(y));
    }
}

// ---------------------------------------------------------------------------
// kv_sum[b,h,d,e] = sum_n k[b,n,h,d]*v[b,n,h,e] ; k_sum[b,h,d] = sum_n k
// ---------------------------------------------------------------------------
__global__ __launch_bounds__(256)
void kv_reduce(const bf16* __restrict__ kn, const bf16* __restrict__ vn,
               float* __restrict__ kv, float* __restrict__ ksum)
{
    const int h = blockIdx.x, b = blockIdx.y;
    __shared__ float Ks[128][48];
    __shared__ float Vs[128][48];
    const int t = threadIdx.x;
    const int d0 = (t >> 4) * 3, e0 = (t & 15) * 3;
    float acc[3][3] = {};
    float ks[3] = {};
    for (int n0 = 0; n0 < NK; n0 += 128) {
        for (int ch = t; ch < 768; ch += 256) {          // 128 rows x 6 chunks
            int r = ch / 6, cc = (ch % 6) * 8;
            size_t base = ((size_t)(b * NK + n0 + r)) * C_ + h * HD + cc;
            s16x8 k8 = *reinterpret_cast<const s16x8*>(kn + base);
            s16x8 v8 = *reinterpret_cast<const s16x8*>(vn + base);
#pragma unroll
            for (int j = 0; j < 8; ++j) {
                Ks[r][cc + j] = bits2f(k8[j]);
                Vs[r][cc + j] = bits2f(v8[j]);
            }
        }
        __syncthreads();
#pragma unroll 4
        for (int r = 0; r < 128; ++r) {
            float k0 = Ks[r][d0], k1 = Ks[r][d0 + 1], k2 = Ks[r][d0 + 2];
            float v0 = Vs[r][e0], v1 = Vs[r][e0 + 1], v2 = Vs[r][e0 + 2];
            acc[0][0] = fmaf(k0, v0, acc[0][0]);
            acc[0][1] = fmaf(k0, v1, acc[0][1]);
            acc[0][2] = fmaf(k0, v2, acc[0][2]);
            acc[1][0] = fmaf(k1, v0, acc[1][0]);
            acc[1][1] = fmaf(k1, v1, acc[1][1]);
            acc[1][2] = fmaf(k1, v2, acc[1][2]);
            acc[2][0] = fmaf(k2, v0, acc[2][0]);
            acc[2][1] = fmaf(k2, v1, acc[2][1]);
            acc[2][2] = fmaf(k2, v2, acc[2][2]);
            if (e0 == 0) { ks[0] += k0; ks[1] += k1; ks[2] += k2; }
        }
        __syncthreads();
    }
    size_t base = (size_t)(b * NH + h) * HD;
#pragma unroll
    for (int i = 0; i < 3; ++i)
#pragma unroll
        for (int j = 0; j < 3; ++j)
            kv[(base + d0 + i) * HD + e0 + j] = acc[i][j];
    if (e0 == 0) {
#pragma unroll
        for (int i = 0; i < 3; ++i) ksum[base + d0 + i] = ks[i];
    }
}

// ---------------------------------------------------------------------------
// attn[b,n,h*48+e] = (sum_d q*kv) / (q.ksum + 1e-8), token-major bf16 out.
// ---------------------------------------------------------------------------
__global__ __launch_bounds__(64)
void attn_numden(const bf16* __restrict__ q, const float* __restrict__ kv,
                 const float* __restrict__ ksum, bf16* __restrict__ attn)
{
    const int nc = blockIdx.x, h = blockIdx.y, b = blockIdx.z;
    __shared__ float skv[48 * 48];
    __shared__ float kss[48];
    const int t = threadIdx.x;
    const float* kvp = kv + (size_t)(b * NH + h) * HD * HD;
    for (int i = t; i < HD * HD; i += 64) skv[i] = kvp[i];
    if (t < HD) kss[t] = ksum[(size_t)(b * NH + h) * HD + t];
    __syncthreads();

    const int n = nc * 64 + t;
    const bf16* qp = q + ((size_t)b * NQ + n) * C_ + h * HD;
    float qv[48];
#pragma unroll
    for (int i = 0; i < 6; ++i) {
        s16x8 v = *reinterpret_cast<const s16x8*>(qp + i * 8);
#pragma unroll
        for (int j = 0; j < 8; ++j) qv[i * 8 + j] = bits2f(v[j]);
    }
    float num[48] = {};
    float den = 0.0f;
#pragma unroll 4
    for (int d = 0; d < 48; ++d) {
        float qd = qv[d];
        den = fmaf(qd, kss[d], den);
#pragma unroll
        for (int e = 0; e < 48; ++e) num[e] = fmaf(qd, skv[d * 48 + e], num[e]);
    }
    float inv = 1.0f / (den + 1e-8f);
    bf16* ap = attn + ((size_t)b * NQ + n) * C_ + h * HD;
#pragma unroll
    for (int i = 0; i < 6; ++i) {
        s16x8 o;
#pragma unroll
        for (int j = 0; j < 8; ++j) o[j] = f2bits(num[i * 8 + j] * inv);
        *reinterpret_cast<s16x8*>(ap + i * 8) = o;
    }
}

// ---------------------------------------------------------------------------
extern "C" void kernel_launch(void* const* d_in, const int* in_sizes, int n_in,
                              void* d_out, int out_size, void* d_ws, size_t ws_size,
                              hipStream_t stream)
{
    const float* query       = (const float*)d_in[0];
    const float* key         = (const float*)d_in[1];
    const float* value       = (const float*)d_in[2];
    const float* ada_gamma   = (const float*)d_in[3];
    const float* ada_beta    = (const float*)d_in[4];
    const float* Wq          = (const float*)d_in[5];
    const float* bq          = (const float*)d_in[6];
    const float* Wk          = (const float*)d_in[7];
    const float* bk          = (const float*)d_in[8];
    const float* Wv          = (const float*)d_in[9];
    const float* bv          = (const float*)d_in[10];
    const float* Wo          = (const float*)d_in[11];
    const float* bo          = (const float*)d_in[12];
    const float* lnq_w       = (const float*)d_in[13];
    const float* lnq_b       = (const float*)d_in[14];
    const float* lnk_w       = (const float*)d_in[15];
    const float* lnk_b       = (const float*)d_in[16];
    const float* attn_scalar = (const float*)d_in[17];
    const float* ffn_gamma   = (const float*)d_in[18];
    const float* ffn_beta    = (const float*)d_in[19];
    const float* W1          = (const float*)d_in[20];
    const float* b1          = (const float*)d_in[21];
    const float* W2          = (const float*)d_in[22];
    const float* b2          = (const float*)d_in[23];
    const float* ffn_scalar  = (const float*)d_in[24];
    const float* final_scalar= (const float*)d_in[25];
    float* out = (float*)d_out;

    // ---- workspace layout (float offsets); peak ~130 MB ----
    float* ws    = (float*)d_ws;
    bf16* qbuf   = (bf16*)(ws);                    // 12.58M bf16 (6.29M fl)
    bf16* attnb  = (bf16*)(ws + 6291456);          // 12.58M bf16
    bf16* kbuf   = (bf16*)(ws + 12582912);         // 3.15M bf16
    bf16* vbuf   = (bf16*)(ws + 14155776);
    bf16* Akb    = (bf16*)(ws + 15728640);
    bf16* Avb    = (bf16*)(ws + 17301504);
    bf16* Aqb    = (bf16*)(ws + 18874368);         // 12.58M bf16
    bf16* hbuf   = (bf16*)(ws);                    // 50.33M bf16 overlay [0,25165824)
    bf16* Awb    = (bf16*)(ws + 25165824);         // 12.58M bf16
    bf16* wqb    = (bf16*)(ws + 31457280);
    bf16* wkb    = wqb + 147456;
    bf16* wvb    = wkb + 147456;
    bf16* wob    = wvb + 147456;
    bf16* w1b    = wob + 147456;
    bf16* w2b    = w1b + 589824;                   // weights end: +884736 fl
    float* kvbuf = ws + 32342016;                  // 147456 fl
    float* ksbuf = kvbuf + 147456;
    float* gx1   = ksbuf + 3072;
    float* sc1b  = gx1 + 3072;
    float* gx2   = sc1b + 3072;
    float* sc2b  = gx2 + 3072;
    // workbuf (`working`, channel-major fp32) lives in d_out.

    // 0. weights -> bf16
    cvt_bf16<<<72, 256, 0, stream>>>(Wq, wqb, 147456);
    cvt_bf16<<<72, 256, 0, stream>>>(Wk, wkb, 147456);
    cvt_bf16<<<72, 256, 0, stream>>>(Wv, wvb, 147456);
    cvt_bf16<<<72, 256, 0, stream>>>(Wo, wob, 147456);
    cvt_bf16<<<288, 256, 0, stream>>>(W1, w1b, 589824);
    cvt_bf16<<<288, 256, 0, stream>>>(W2, w2b, 589824);

    // 1. GRN(query) scale
    grn_gx<<<B_ * C_, 256, 0, stream>>>(query, gx1, NQ);
    grn_scale<<<B_, 384, 0, stream>>>(gx1, ada_gamma, sc1b);

    // 2. transposed bf16 A-matrices (GRN fused for q)
    t2b<true ><<<dim3(64, 6, B_), 256, 0, stream>>>(query, Aqb, sc1b, ada_beta, NQ);
    t2b<false><<<dim3(16, 6, B_), 256, 0, stream>>>(key,   Akb, nullptr, nullptr, NK);
    t2b<false><<<dim3(16, 6, B_), 256, 0, stream>>>(value, Avb, nullptr, nullptr, NK);

    // 3. Q/K/V projections (MFMA, bf16 token-major out)
    gemm_mfma<0><<<dim3(256, 3), 256, 0, stream>>>(Aqb, wqb, bq, 384, 384, NQ,
        qbuf, nullptr, nullptr, nullptr, nullptr);
    gemm_mfma<0><<<dim3(64, 3), 256, 0, stream>>>(Akb, wkb, bk, 384, 384, NK,
        kbuf, nullptr, nullptr, nullptr, nullptr);
    gemm_mfma<0><<<dim3(64, 3), 256, 0, stream>>>(Avb, wvb, bv, 384, 384, NK,
        vbuf, nullptr, nullptr, nullptr, nullptr);

    // 4. LN + elu+1 in place
    ln_elu_b<<<8192, 256, 0, stream>>>(qbuf, lnq_w, lnq_b);
    ln_elu_b<<<2048, 256, 0, stream>>>(kbuf, lnk_w, lnk_b);

    // 5. kv_sum / k_sum and linear attention
    kv_reduce<<<dim3(NH, B_), 256, 0, stream>>>(kbuf, vbuf, kvbuf, ksbuf);
    attn_numden<<<dim3(NQ / 64, NH, B_), 64, 0, stream>>>(qbuf, kvbuf, ksbuf, attnb);

    // 6. Wo projection + residual -> working (channel-major fp32, in d_out)
    gemm_mfma<2><<<dim3(256, 3), 256, 0, stream>>>(attnb, wob, bo, 384, 384, NQ,
        nullptr, out, query, attn_scalar, nullptr);

    // 7. GRN(working) -> Aw (bf16 token-major)
    grn_gx<<<B_ * C_, 256, 0, stream>>>(out, gx2, NQ);
    grn_scale<<<B_, 384, 0, stream>>>(gx2, ffn_gamma, sc2b);
    t2b<true><<<dim3(64, 6, B_), 256, 0, stream>>>(out, Awb, sc2b, ffn_beta, NQ);

    // 8. FFN W1 + silu -> h (bf16 token-major)
    gemm_mfma<1><<<dim3(256, 12), 256, 0, stream>>>(Awb, w1b, b1, 1536, 384, NQ,
        hbuf, nullptr, nullptr, nullptr, nullptr);

    // 9. FFN W2 + residuals -> out (channel-major fp32)
    gemm_mfma<3><<<dim3(256, 3), 256, 0, stream>>>(hbuf, w2b, b2, 384, 1536, NQ,
        nullptr, out, query, ffn_scalar, final_scalar);
}

// Round 5
// 579.185 us; speedup vs baseline: 1.0750x; 1.0750x over previous
//
#include <hip/hip_runtime.h>
#include <hip/hip_bf16.h>
#include <cmath>

typedef __hip_bfloat16 bf16;
typedef __attribute__((ext_vector_type(8))) short s16x8;
typedef __attribute__((ext_vector_type(4))) float f32x4;

#define B_  8
#define C_  384
#define NQ  4096
#define NK  1024
#define NH  8
#define HD  48
#define F_  1536

__device__ __forceinline__ float bits2f(short s) {
    unsigned int u = ((unsigned int)(unsigned short)s) << 16;
    float f; __builtin_memcpy(&f, &u, 4); return f;
}
__device__ __forceinline__ short f2bits(float f) {
    bf16 h = __float2bfloat16(f);
    short s; __builtin_memcpy(&s, &h, 2); return s;
}

// async global->LDS, 16 B per lane; l must be wave-uniform (HW adds lane*16)
__device__ __forceinline__ void gload16(const bf16* g, bf16* l) {
    __builtin_amdgcn_global_load_lds(
        (const __attribute__((address_space(1))) void*)g,
        (__attribute__((address_space(3))) void*)l, 16, 0, 0);
}

// ---------------------------------------------------------------------------
// GRN step 1: gx[b*C+c] = sqrt(sum over spatial of x^2). One block per (b,c).
// ---------------------------------------------------------------------------
__global__ __launch_bounds__(256)
void grn_gx(const float* __restrict__ x, float* __restrict__ gx, int nsp)
{
    size_t base = (size_t)blockIdx.x * nsp;
    float s = 0.0f;
    for (int i = threadIdx.x * 4; i < nsp; i += 256 * 4) {
        float4 v = *reinterpret_cast<const float4*>(&x[base + i]);
        s += v.x * v.x + v.y * v.y + v.z * v.z + v.w * v.w;
    }
    for (int m = 32; m; m >>= 1) s += __shfl_xor(s, m);
    __shared__ float sh[4];
    if ((threadIdx.x & 63) == 0) sh[threadIdx.x >> 6] = s;
    __syncthreads();
    if (threadIdx.x == 0) gx[blockIdx.x] = sqrtf(sh[0] + sh[1] + sh[2] + sh[3]);
}

// ---------------------------------------------------------------------------
// GRN step 2: scale[b*C+c] = (1+gamma[c]) * gx/(mean_c(gx)+eps) + 1
// ---------------------------------------------------------------------------
__global__ __launch_bounds__(384)
void grn_scale(const float* __restrict__ gx, const float* __restrict__ gamma,
               float* __restrict__ scale)
{
    int b = blockIdx.x;
    int c = threadIdx.x;            // 384 threads
    float g = gx[b * C_ + c];
    float s = g;
    for (int m = 32; m; m >>= 1) s += __shfl_xor(s, m);
    __shared__ float sh[6];
    if ((c & 63) == 0) sh[c >> 6] = s;
    __syncthreads();
    if (c == 0) {
        float t = 0.0f;
        for (int i = 0; i < 6; ++i) t += sh[i];
        sh[0] = t / (float)C_;
    }
    __syncthreads();
    float nx = g / (sh[0] + 1e-6f);
    scale[b * C_ + c] = (1.0f + gamma[c]) * nx + 1.0f;
}

// ---------------------------------------------------------------------------
// fp32 -> bf16 convert (weights). n multiple of 2048.
// ---------------------------------------------------------------------------
__global__ __launch_bounds__(256)
void cvt_bf16(const float* __restrict__ src, bf16* __restrict__ dst, int n)
{
    int i = (blockIdx.x * 256 + threadIdx.x) * 8;
    if (i >= n) return;
    float4 a = *reinterpret_cast<const float4*>(src + i);
    float4 b = *reinterpret_cast<const float4*>(src + i + 4);
    s16x8 o;
    o[0] = f2bits(a.x); o[1] = f2bits(a.y); o[2] = f2bits(a.z); o[3] = f2bits(a.w);
    o[4] = f2bits(b.x); o[5] = f2bits(b.y); o[6] = f2bits(b.z); o[7] = f2bits(b.w);
    *reinterpret_cast<s16x8*>(dst + i) = o;
}

// ---------------------------------------------------------------------------
// Transpose channel-major fp32 [b][c][m] -> token-major bf16 [b][m][c],
// optional fused affine (GRN): v*scale[b,c] + shift[c]. 64x64 tiles.
// ---------------------------------------------------------------------------
template<bool SCALED>
__global__ __launch_bounds__(256)
void t2b(const float* __restrict__ src, bf16* __restrict__ dst,
         const float* __restrict__ scale, const float* __restrict__ shift, int Msp)
{
    const int b = blockIdx.z, c0 = blockIdx.y * 64, m0 = blockIdx.x * 64;
    __shared__ float T[64][65];
    const int tr = threadIdx.x >> 6, tc = threadIdx.x & 63;
    const float* sp = src + ((size_t)b * C_ + c0) * Msp + m0;
#pragma unroll
    for (int i = 0; i < 16; ++i)
        T[i * 4 + tr][tc] = sp[(size_t)(i * 4 + tr) * Msp + tc];
    __syncthreads();
    const int c = c0 + tc;
    float scl = 1.0f, sh = 0.0f;
    if constexpr (SCALED) { scl = scale[b * C_ + c]; sh = shift[c]; }
    bf16* dp = dst + ((size_t)b * Msp + m0) * C_ + c;
#pragma unroll
    for (int i = 0; i < 16; ++i) {
        int m = i * 4 + tr;
        dp[(size_t)m * C_] = __float2bfloat16(T[tc][m] * scl + sh);
    }
}

// ---------------------------------------------------------------------------
// MFMA GEMM, 2-phase double-buffered (T3-minimum):
//   out[m][n] = sum_k A[m][k]*W[n][k], bf16 inputs, k-contiguous.
// 128x128 tile, BK=32, 4 waves (2x2), 4x4 16x16x32 frags per wave.
// Staging via global_load_lds width=16 into LINEAR LDS [128][32] per buffer.
// Loop: stage(next buf) -> compute(cur buf) -> barrier (drains vmcnt).
// Load latency overlaps the ds_read+MFMA of the current tile.
// EPI: 0 = bf16 token-major (+bias), 1 = +silu, bf16 token-major,
//      2 = channel-major fp32: outF = query + val*sc1
//      3 = channel-major fp32: outF = query + (outF + val*sc1)*sc2
// ---------------------------------------------------------------------------
template<int EPI>
__global__ __launch_bounds__(256)
void gemm_mfma(const bf16* __restrict__ A, const bf16* __restrict__ W,
               const float* __restrict__ bias, int N, int K, int Mspat,
               bf16* __restrict__ outB, float* __restrict__ outF,
               const float* __restrict__ query,
               const float* __restrict__ sc1, const float* __restrict__ sc2)
{
    __shared__ __align__(16) char smem_raw[33792];
    // dbuf p in {0,1}: As at p*16384, Bs at p*16384 + 8192 (byte offsets)
    const int tid  = threadIdx.x;
    const int lane = tid & 63, wave = tid >> 6;
    const int wm = wave >> 1, wn = wave & 1;
    const int lrow = lane & 15, lk8 = lane >> 4;
    const int mrow0 = blockIdx.x * 128;
    const int nt    = blockIdx.y * 128;

    // staging: wave w covers rows [w*32, w*32+32), 2 instrs of 16 rows each;
    // lane l -> row r0+(l>>2), k-slot (l&3)*8; LDS offset = lane*16 B (linear).
    const int r0   = wave * 32;               // uniform per wave
    const int srow = r0 + (lane >> 2);
    const int sk   = (lane & 3) * 8;
    const bf16* Ag = A + (size_t)(mrow0 + srow) * K + sk;
    const bf16* Wg = W + (size_t)(nt    + srow) * K + sk;
    f32x4 acc[4][4] = {};

    auto stage = [&](int p, int kt) {
        bf16* AsD = (bf16*)(smem_raw + p * 16384) + r0 * 32;
        bf16* BsD = (bf16*)(smem_raw + p * 16384 + 8192) + r0 * 32;
        gload16(Ag + kt,                  AsD);
        gload16(Ag + kt + (size_t)16 * K, AsD + 16 * 32);
        gload16(Wg + kt,                  BsD);
        gload16(Wg + kt + (size_t)16 * K, BsD + 16 * 32);
    };
    auto compute = [&](int p) {
        const bf16* As = (const bf16*)(smem_raw + p * 16384);
        const bf16* Bs = (const bf16*)(smem_raw + p * 16384 + 8192);
        s16x8 af[4], bfr[4];
#pragma unroll
        for (int m = 0; m < 4; ++m)
            af[m] = *reinterpret_cast<const s16x8*>(As + (wm * 64 + m * 16 + lrow) * 32 + lk8 * 8);
#pragma unroll
        for (int n = 0; n < 4; ++n)
            bfr[n] = *reinterpret_cast<const s16x8*>(Bs + (wn * 64 + n * 16 + lrow) * 32 + lk8 * 8);
#pragma unroll
        for (int m = 0; m < 4; ++m)
#pragma unroll
            for (int n = 0; n < 4; ++n)
                acc[m][n] = __builtin_amdgcn_mfma_f32_16x16x32_bf16(af[m], bfr[n], acc[m][n], 0, 0, 0);
    };

    stage(0, 0);
    __syncthreads();                         // buf0 staged
    int cur = 0;
    for (int kt = 32; kt < K; kt += 32) {
        stage(cur ^ 1, kt);                  // async prefetch next tile
        compute(cur);                        // overlaps load latency
        __syncthreads();                     // drains vmcnt -> next buf ready
        cur ^= 1;
    }
    compute(cur);                            // last tile (already staged)
    __syncthreads();                         // frag reads done before smem reuse

    if constexpr (EPI <= 1) {
        bf16* Cs = (bf16*)smem_raw;          // [128][128]
#pragma unroll
        for (int m = 0; m < 4; ++m)
#pragma unroll
            for (int n = 0; n < 4; ++n) {
                int col = wn * 64 + n * 16 + lrow;
                float bv = bias[nt + col];
#pragma unroll
                for (int j = 0; j < 4; ++j) {
                    int row = wm * 64 + m * 16 + lk8 * 4 + j;
                    float v = acc[m][n][j] + bv;
                    if constexpr (EPI == 1) v = v / (1.0f + __expf(-v));
                    Cs[row * 128 + col] = __float2bfloat16(v);
                }
            }
        __syncthreads();
#pragma unroll
        for (int p = 0; p < 8; ++p) {
            int e = p * 256 + tid;
            int row = e >> 4, ch = (e & 15) * 8;
            *reinterpret_cast<s16x8*>(outB + (size_t)(mrow0 + row) * N + nt + ch) =
                *reinterpret_cast<const s16x8*>(Cs + row * 128 + ch);
        }
    } else {
        float* Cs2 = (float*)smem_raw;       // [64][132] fp32
        const int b = mrow0 / Mspat;
        const int mloc0 = mrow0 - b * Mspat;
        for (int half = 0; half < 2; ++half) {
            if (half) __syncthreads();
            if (wn == half) {
#pragma unroll
                for (int m = 0; m < 4; ++m)
#pragma unroll
                    for (int n = 0; n < 4; ++n) {
                        int crow = n * 16 + lrow;
                        float bv = bias[nt + half * 64 + crow];
#pragma unroll
                        for (int j = 0; j < 4; ++j) {
                            int mcol = wm * 64 + m * 16 + lk8 * 4 + j;
                            Cs2[crow * 132 + mcol] = acc[m][n][j] + bv;
                        }
                    }
            }
            __syncthreads();
#pragma unroll
            for (int p = 0; p < 8; ++p) {
                int e = p * 256 + tid;
                int crow = e >> 5, m4 = (e & 31) * 4;
                int c = nt + half * 64 + crow;
                size_t off = ((size_t)b * C_ + c) * Mspat + mloc0 + m4;
                float4 v  = *reinterpret_cast<const float4*>(Cs2 + crow * 132 + m4);
                float4 q4 = *reinterpret_cast<const float4*>(query + off);
                float s1 = sc1[c];
                float4 o;
                if constexpr (EPI == 2) {
                    o.x = q4.x + v.x * s1;
                    o.y = q4.y + v.y * s1;
                    o.z = q4.z + v.z * s1;
                    o.w = q4.w + v.w * s1;
                } else {
                    float4 w4 = *reinterpret_cast<const float4*>(outF + off);
                    float s2 = sc2[c];
                    o.x = q4.x + (w4.x + v.x * s1) * s2;
                    o.y = q4.y + (w4.y + v.y * s1) * s2;
                    o.z = q4.z + (w4.z + v.z * s1) * s2;
                    o.w = q4.w + (w4.w + v.w * s1) * s2;
                }
                *reinterpret_cast<float4*>(outF + off) = o;
            }
        }
    }
}

// ---------------------------------------------------------------------------
// LayerNorm(384) + elu+1 over bf16 token-major rows, in place. 1 wave/row.
// ---------------------------------------------------------------------------
__global__ __launch_bounds__(256)
void ln_elu_b(bf16* __restrict__ x, const float* __restrict__ w,
              const float* __restrict__ bb)
{
    int lane = threadIdx.x & 63, wid = threadIdx.x >> 6;
    int row = blockIdx.x * 4 + wid;
    bf16* p = x + (size_t)row * C_;
    float v[6];
#pragma unroll
    for (int i = 0; i < 6; ++i) v[i] = __bfloat162float(p[lane + i * 64]);
    float s = 0.0f;
#pragma unroll
    for (int i = 0; i < 6; ++i) s += v[i];
    for (int m = 32; m; m >>= 1) s += __shfl_xor(s, m);
    float mu = s / (float)C_;
    float vs = 0.0f;
#pragma unroll
    for (int i = 0; i < 6; ++i) { float d = v[i] - mu; vs += d * d; }
    for (int m = 32; m; m >>= 1) vs += __shfl_xor(vs, m);
    float inv = rsqrtf(vs / (float)C_ + 1e-5f);
#pragma unroll
    for (int i = 0; i < 6; ++i) {
        int c = lane + i * 64;
        float y = (v[i] - mu) * inv * w[c] + bb[c];
        p[c] = __float2bfloat16((y > 0.0f) ? (y + 1.0f) : __expf(y));
    }
}

// ---------------------------------------------------------------------------
// kv_sum[b,h,d,e] = sum_n k[b,n,h,d]*v[b,n,h,e] ; k_sum[b,h,d] = sum_n k
// ---------------------------------------------------------------------------
__global__ __launch_bounds__(256)
void kv_reduce(const bf16* __restrict__ kn, const bf16* __restrict__ vn,
               float* __restrict__ kv, float* __restrict__ ksum)
{
    const int h = blockIdx.x, b = blockIdx.y;
    __shared__ float Ks[128][48];
    __shared__ float Vs[128][48];
    const int t = threadIdx.x;
    const int d0 = (t >> 4) * 3, e0 = (t & 15) * 3;
    float acc[3][3] = {};
    float ks[3] = {};
    for (int n0 = 0; n0 < NK; n0 += 128) {
        for (int ch = t; ch < 768; ch += 256) {          // 128 rows x 6 chunks
            int r = ch / 6, cc = (ch % 6) * 8;
            size_t base = ((size_t)(b * NK + n0 + r)) * C_ + h * HD + cc;
            s16x8 k8 = *reinterpret_cast<const s16x8*>(kn + base);
            s16x8 v8 = *reinterpret_cast<const s16x8*>(vn + base);
#pragma unroll
            for (int j = 0; j < 8; ++j) {
                Ks[r][cc + j] = bits2f(k8[j]);
                Vs[r][cc + j] = bits2f(v8[j]);
            }
        }
        __syncthreads();
#pragma unroll 4
        for (int r = 0; r < 128; ++r) {
            float k0 = Ks[r][d0], k1 = Ks[r][d0 + 1], k2 = Ks[r][d0 + 2];
            float v0 = Vs[r][e0], v1 = Vs[r][e0 + 1], v2 = Vs[r][e0 + 2];
            acc[0][0] = fmaf(k0, v0, acc[0][0]);
            acc[0][1] = fmaf(k0, v1, acc[0][1]);
            acc[0][2] = fmaf(k0, v2, acc[0][2]);
            acc[1][0] = fmaf(k1, v0, acc[1][0]);
            acc[1][1] = fmaf(k1, v1, acc[1][1]);
            acc[1][2] = fmaf(k1, v2, acc[1][2]);
            acc[2][0] = fmaf(k2, v0, acc[2][0]);
            acc[2][1] = fmaf(k2, v1, acc[2][1]);
            acc[2][2] = fmaf(k2, v2, acc[2][2]);
            if (e0 == 0) { ks[0] += k0; ks[1] += k1; ks[2] += k2; }
        }
        __syncthreads();
    }
    size_t base = (size_t)(b * NH + h) * HD;
#pragma unroll
    for (int i = 0; i < 3; ++i)
#pragma unroll
        for (int j = 0; j < 3; ++j)
            kv[(base + d0 + i) * HD + e0 + j] = acc[i][j];
    if (e0 == 0) {
#pragma unroll
        for (int i = 0; i < 3; ++i) ksum[base + d0 + i] = ks[i];
    }
}

// ---------------------------------------------------------------------------
// attn[b,n,h*48+e] = (sum_d q*kv) / (q.ksum + 1e-8), token-major bf16 out.
// ---------------------------------------------------------------------------
__global__ __launch_bounds__(64)
void attn_numden(const bf16* __restrict__ q, const float* __restrict__ kv,
                 const float* __restrict__ ksum, bf16* __restrict__ attn)
{
    const int nc = blockIdx.x, h = blockIdx.y, b = blockIdx.z;
    __shared__ float skv[48 * 48];
    __shared__ float kss[48];
    const int t = threadIdx.x;
    const float* kvp = kv + (size_t)(b * NH + h) * HD * HD;
    for (int i = t; i < HD * HD; i += 64) skv[i] = kvp[i];
    if (t < HD) kss[t] = ksum[(size_t)(b * NH + h) * HD + t];
    __syncthreads();

    const int n = nc * 64 + t;
    const bf16* qp = q + ((size_t)b * NQ + n) * C_ + h * HD;
    float qv[48];
#pragma unroll
    for (int i = 0; i < 6; ++i) {
        s16x8 v = *reinterpret_cast<const s16x8*>(qp + i * 8);
#pragma unroll
        for (int j = 0; j < 8; ++j) qv[i * 8 + j] = bits2f(v[j]);
    }
    float num[48] = {};
    float den = 0.0f;
#pragma unroll 4
    for (int d = 0; d < 48; ++d) {
        float qd = qv[d];
        den = fmaf(qd, kss[d], den);
#pragma unroll
        for (int e = 0; e < 48; ++e) num[e] = fmaf(qd, skv[d * 48 + e], num[e]);
    }
    float inv = 1.0f / (den + 1e-8f);
    bf16* ap = attn + ((size_t)b * NQ + n) * C_ + h * HD;
#pragma unroll
    for (int i = 0; i < 6; ++i) {
        s16x8 o;
#pragma unroll
        for (int j = 0; j < 8; ++j) o[j] = f2bits(num[i * 8 + j] * inv);
        *reinterpret_cast<s16x8*>(ap + i * 8) = o;
    }
}

// ---------------------------------------------------------------------------
extern "C" void kernel_launch(void* const* d_in, const int* in_sizes, int n_in,
                              void* d_out, int out_size, void* d_ws, size_t ws_size,
                              hipStream_t stream)
{
    const float* query       = (const float*)d_in[0];
    const float* key         = (const float*)d_in[1];
    const float* value       = (const float*)d_in[2];
    const float* ada_gamma   = (const float*)d_in[3];
    const float* ada_beta    = (const float*)d_in[4];
    const float* Wq          = (const float*)d_in[5];
    const float* bq          = (const float*)d_in[6];
    const float* Wk          = (const float*)d_in[7];
    const float* bk          = (const float*)d_in[8];
    const float* Wv          = (const float*)d_in[9];
    const float* bv          = (const float*)d_in[10];
    const float* Wo          = (const float*)d_in[11];
    const float* bo          = (const float*)d_in[12];
    const float* lnq_w       = (const float*)d_in[13];
    const float* lnq_b       = (const float*)d_in[14];
    const float* lnk_w       = (const float*)d_in[15];
    const float* lnk_b       = (const float*)d_in[16];
    const float* attn_scalar = (const float*)d_in[17];
    const float* ffn_gamma   = (const float*)d_in[18];
    const float* ffn_beta    = (const float*)d_in[19];
    const float* W1          = (const float*)d_in[20];
    const float* b1          = (const float*)d_in[21];
    const float* W2          = (const float*)d_in[22];
    const float* b2          = (const float*)d_in[23];
    const float* ffn_scalar  = (const float*)d_in[24];
    const float* final_scalar= (const float*)d_in[25];
    float* out = (float*)d_out;

    // ---- workspace layout (float offsets); peak ~130 MB ----
    float* ws    = (float*)d_ws;
    bf16* qbuf   = (bf16*)(ws);                    // 12.58M bf16 (6.29M fl)
    bf16* attnb  = (bf16*)(ws + 6291456);          // 12.58M bf16
    bf16* kbuf   = (bf16*)(ws + 12582912);         // 3.15M bf16
    bf16* vbuf   = (bf16*)(ws + 14155776);
    bf16* Akb    = (bf16*)(ws + 15728640);
    bf16* Avb    = (bf16*)(ws + 17301504);
    bf16* Aqb    = (bf16*)(ws + 18874368);         // 12.58M bf16
    bf16* hbuf   = (bf16*)(ws);                    // 50.33M bf16 overlay [0,25165824)
    bf16* Awb    = (bf16*)(ws + 25165824);         // 12.58M bf16
    bf16* wqb    = (bf16*)(ws + 31457280);
    bf16* wkb    = wqb + 147456;
    bf16* wvb    = wkb + 147456;
    bf16* wob    = wvb + 147456;
    bf16* w1b    = wob + 147456;
    bf16* w2b    = w1b + 589824;                   // weights end: +884736 fl
    float* kvbuf = ws + 32342016;                  // 147456 fl
    float* ksbuf = kvbuf + 147456;
    float* gx1   = ksbuf + 3072;
    float* sc1b  = gx1 + 3072;
    float* gx2   = sc1b + 3072;
    float* sc2b  = gx2 + 3072;
    // workbuf (`working`, channel-major fp32) lives in d_out.

    // 0. weights -> bf16
    cvt_bf16<<<72, 256, 0, stream>>>(Wq, wqb, 147456);
    cvt_bf16<<<72, 256, 0, stream>>>(Wk, wkb, 147456);
    cvt_bf16<<<72, 256, 0, stream>>>(Wv, wvb, 147456);
    cvt_bf16<<<72, 256, 0, stream>>>(Wo, wob, 147456);
    cvt_bf16<<<288, 256, 0, stream>>>(W1, w1b, 589824);
    cvt_bf16<<<288, 256, 0, stream>>>(W2, w2b, 589824);

    // 1. GRN(query) scale
    grn_gx<<<B_ * C_, 256, 0, stream>>>(query, gx1, NQ);
    grn_scale<<<B_, 384, 0, stream>>>(gx1, ada_gamma, sc1b);

    // 2. transposed bf16 A-matrices (GRN fused for q)
    t2b<true ><<<dim3(64, 6, B_), 256, 0, stream>>>(query, Aqb, sc1b, ada_beta, NQ);
    t2b<false><<<dim3(16, 6, B_), 256, 0, stream>>>(key,   Akb, nullptr, nullptr, NK);
    t2b<false><<<dim3(16, 6, B_), 256, 0, stream>>>(value, Avb, nullptr, nullptr, NK);

    // 3. Q/K/V projections (MFMA, bf16 token-major out)
    gemm_mfma<0><<<dim3(256, 3), 256, 0, stream>>>(Aqb, wqb, bq, 384, 384, NQ,
        qbuf, nullptr, nullptr, nullptr, nullptr);
    gemm_mfma<0><<<dim3(64, 3), 256, 0, stream>>>(Akb, wkb, bk, 384, 384, NK,
        kbuf, nullptr, nullptr, nullptr, nullptr);
    gemm_mfma<0><<<dim3(64, 3), 256, 0, stream>>>(Avb, wvb, bv, 384, 384, NK,
        vbuf, nullptr, nullptr, nullptr, nullptr);

    // 4. LN + elu+1 in place
    ln_elu_b<<<8192, 256, 0, stream>>>(qbuf, lnq_w, lnq_b);
    ln_elu_b<<<2048, 256, 0, stream>>>(kbuf, lnk_w, lnk_b);

    // 5. kv_sum / k_sum and linear attention
    kv_reduce<<<dim3(NH, B_), 256, 0, stream>>>(kbuf, vbuf, kvbuf, ksbuf);
    attn_numden<<<dim3(NQ / 64, NH, B_), 64, 0, stream>>>(qbuf, kvbuf, ksbuf, attnb);

    // 6. Wo projection + residual -> working (channel-major fp32, in d_out)
    gemm_mfma<2><<<dim3(256, 3), 256, 0, stream>>>(attnb, wob, bo, 384, 384, NQ,
        nullptr, out, query, attn_scalar, nullptr);

    // 7. GRN(working) -> Aw (bf16 token-major)
    grn_gx<<<B_ * C_, 256, 0, stream>>>(out, gx2, NQ);
    grn_scale<<<B_, 384, 0, stream>>>(gx2, ffn_gamma, sc2b);
    t2b<true><<<dim3(64, 6, B_), 256, 0, stream>>>(out, Awb, sc2b, ffn_beta, NQ);

    // 8. FFN W1 + silu -> h (bf16 token-major)
    gemm_mfma<1><<<dim3(256, 12), 256, 0, stream>>>(Awb, w1b, b1, 1536, 384, NQ,
        hbuf, nullptr, nullptr, nullptr, nullptr);

    // 9. FFN W2 + residuals -> out (channel-major fp32)
    gemm_mfma<3><<<dim3(256, 3), 256, 0, stream>>>(hbuf, w2b, b2, 384, 1536, NQ,
        nullptr, out, query, ffn_scalar, final_scalar);
}

// Round 6
// 553.957 us; speedup vs baseline: 1.1239x; 1.0455x over previous
//
#include <hip/hip_runtime.h>
#include <hip/hip_bf16.h>
#include <cmath>

typedef __hip_bfloat16 bf16;
typedef __attribute__((ext_vector_type(8))) short s16x8;
typedef __attribute__((ext_vector_type(4))) float f32x4;

#define B_  8
#define C_  384
#define NQ  4096
#define NK  1024
#define NH  8
#define HD  48
#define F_  1536

__device__ __forceinline__ float bits2f(short s) {
    unsigned int u = ((unsigned int)(unsigned short)s) << 16;
    float f; __builtin_memcpy(&f, &u, 4); return f;
}
__device__ __forceinline__ short f2bits(float f) {
    bf16 h = __float2bfloat16(f);
    short s; __builtin_memcpy(&s, &h, 2); return s;
}

// async global->LDS, 16 B per lane; l must be wave-uniform (HW adds lane*16)
__device__ __forceinline__ void gload16(const bf16* g, bf16* l) {
    __builtin_amdgcn_global_load_lds(
        (const __attribute__((address_space(1))) void*)g,
        (__attribute__((address_space(3))) void*)l, 16, 0, 0);
}

// ---------------------------------------------------------------------------
// GRN step 1: gx[b*C+c] = sqrt(sum over spatial of x^2). One block per (b,c).
// ---------------------------------------------------------------------------
__global__ __launch_bounds__(256)
void grn_gx(const float* __restrict__ x, float* __restrict__ gx, int nsp)
{
    size_t base = (size_t)blockIdx.x * nsp;
    float s = 0.0f;
    for (int i = threadIdx.x * 4; i < nsp; i += 256 * 4) {
        float4 v = *reinterpret_cast<const float4*>(&x[base + i]);
        s += v.x * v.x + v.y * v.y + v.z * v.z + v.w * v.w;
    }
    for (int m = 32; m; m >>= 1) s += __shfl_xor(s, m);
    __shared__ float sh[4];
    if ((threadIdx.x & 63) == 0) sh[threadIdx.x >> 6] = s;
    __syncthreads();
    if (threadIdx.x == 0) gx[blockIdx.x] = sqrtf(sh[0] + sh[1] + sh[2] + sh[3]);
}

// ---------------------------------------------------------------------------
// GRN step 2: scale[b*C+c] = (1+gamma[c]) * gx/(mean_c(gx)+eps) + 1
// ---------------------------------------------------------------------------
__global__ __launch_bounds__(384)
void grn_scale(const float* __restrict__ gx, const float* __restrict__ gamma,
               float* __restrict__ scale)
{
    int b = blockIdx.x;
    int c = threadIdx.x;            // 384 threads
    float g = gx[b * C_ + c];
    float s = g;
    for (int m = 32; m; m >>= 1) s += __shfl_xor(s, m);
    __shared__ float sh[6];
    if ((c & 63) == 0) sh[c >> 6] = s;
    __syncthreads();
    if (c == 0) {
        float t = 0.0f;
        for (int i = 0; i < 6; ++i) t += sh[i];
        sh[0] = t / (float)C_;
    }
    __syncthreads();
    float nx = g / (sh[0] + 1e-6f);
    scale[b * C_ + c] = (1.0f + gamma[c]) * nx + 1.0f;
}

// ---------------------------------------------------------------------------
// fp32 -> bf16 convert (weights). n multiple of 2048.
// ---------------------------------------------------------------------------
__global__ __launch_bounds__(256)
void cvt_bf16(const float* __restrict__ src, bf16* __restrict__ dst, int n)
{
    int i = (blockIdx.x * 256 + threadIdx.x) * 8;
    if (i >= n) return;
    float4 a = *reinterpret_cast<const float4*>(src + i);
    float4 b = *reinterpret_cast<const float4*>(src + i + 4);
    s16x8 o;
    o[0] = f2bits(a.x); o[1] = f2bits(a.y); o[2] = f2bits(a.z); o[3] = f2bits(a.w);
    o[4] = f2bits(b.x); o[5] = f2bits(b.y); o[6] = f2bits(b.z); o[7] = f2bits(b.w);
    *reinterpret_cast<s16x8*>(dst + i) = o;
}

// ---------------------------------------------------------------------------
// Transpose channel-major fp32 [b][c][m] -> token-major bf16 [b][m][c],
// optional fused affine (GRN): v*scale[b,c] + shift[c]. 64x64 tiles.
// ---------------------------------------------------------------------------
template<bool SCALED>
__global__ __launch_bounds__(256)
void t2b(const float* __restrict__ src, bf16* __restrict__ dst,
         const float* __restrict__ scale, const float* __restrict__ shift, int Msp)
{
    const int b = blockIdx.z, c0 = blockIdx.y * 64, m0 = blockIdx.x * 64;
    __shared__ float T[64][65];
    const int tr = threadIdx.x >> 6, tc = threadIdx.x & 63;
    const float* sp = src + ((size_t)b * C_ + c0) * Msp + m0;
#pragma unroll
    for (int i = 0; i < 16; ++i)
        T[i * 4 + tr][tc] = sp[(size_t)(i * 4 + tr) * Msp + tc];
    __syncthreads();
    const int c = c0 + tc;
    float scl = 1.0f, sh = 0.0f;
    if constexpr (SCALED) { scl = scale[b * C_ + c]; sh = shift[c]; }
    bf16* dp = dst + ((size_t)b * Msp + m0) * C_ + c;
#pragma unroll
    for (int i = 0; i < 16; ++i) {
        int m = i * 4 + tr;
        dp[(size_t)m * C_] = __float2bfloat16(T[tc][m] * scl + sh);
    }
}

// ---------------------------------------------------------------------------
// MFMA GEMM, 2-phase double-buffer with COUNTED vmcnt (T4):
//   out[m][n] = sum_k A[m][k]*W[n][k], bf16 inputs, k-contiguous.
// 128x128 tile, BK=32, 4 waves (2x2), 4x4 16x16x32 frags per wave.
// Staging via global_load_lds width=16 into LINEAR LDS [128][32] per buffer.
// K-loop uses raw s_barrier + s_waitcnt vmcnt(4): the next tile's 4 loads
// stay in flight across both barriers (never drain to 0 in the loop).
// Each wave waits only for ITS OWN 4 oldest loads before barrier A; barrier A
// then guarantees every wave's tile-t rows are in LDS (cross-wave visibility).
// EPI: 0 = bf16 token-major (+bias), 1 = +silu, bf16 token-major,
//      2 = channel-major fp32: outF = query + val*sc1
//      3 = channel-major fp32: outF = query + (outF + val*sc1)*sc2
// ---------------------------------------------------------------------------
template<int EPI>
__global__ __launch_bounds__(256)
void gemm_mfma(const bf16* __restrict__ A, const bf16* __restrict__ W,
               const float* __restrict__ bias, int N, int K, int Mspat,
               bf16* __restrict__ outB, float* __restrict__ outF,
               const float* __restrict__ query,
               const float* __restrict__ sc1, const float* __restrict__ sc2)
{
    __shared__ __align__(16) char smem_raw[33792];
    // dbuf p in {0,1}: As at p*16384, Bs at p*16384 + 8192 (byte offsets)
    const int tid  = threadIdx.x;
    const int lane = tid & 63, wave = tid >> 6;
    const int wm = wave >> 1, wn = wave & 1;
    const int lrow = lane & 15, lk8 = lane >> 4;
    const int mrow0 = blockIdx.x * 128;
    const int nt    = blockIdx.y * 128;

    // staging: wave w covers rows [w*32, w*32+32), 2 instrs of 16 rows each;
    // lane l -> row r0+(l>>2), k-slot (l&3)*8; LDS offset = lane*16 B (linear).
    const int r0   = wave * 32;               // uniform per wave
    const int srow = r0 + (lane >> 2);
    const int sk   = (lane & 3) * 8;
    const bf16* Ag = A + (size_t)(mrow0 + srow) * K + sk;
    const bf16* Wg = W + (size_t)(nt    + srow) * K + sk;
    f32x4 acc[4][4] = {};

    auto stage = [&](int p, int kt) {         // 4 vmem ops per wave
        bf16* AsD = (bf16*)(smem_raw + p * 16384) + r0 * 32;
        bf16* BsD = (bf16*)(smem_raw + p * 16384 + 8192) + r0 * 32;
        gload16(Ag + kt,                  AsD);
        gload16(Ag + kt + (size_t)16 * K, AsD + 16 * 32);
        gload16(Wg + kt,                  BsD);
        gload16(Wg + kt + (size_t)16 * K, BsD + 16 * 32);
    };
    auto compute = [&](int p) {
        const bf16* As = (const bf16*)(smem_raw + p * 16384);
        const bf16* Bs = (const bf16*)(smem_raw + p * 16384 + 8192);
        s16x8 af[4], bfr[4];
#pragma unroll
        for (int m = 0; m < 4; ++m)
            af[m] = *reinterpret_cast<const s16x8*>(As + (wm * 64 + m * 16 + lrow) * 32 + lk8 * 8);
#pragma unroll
        for (int n = 0; n < 4; ++n)
            bfr[n] = *reinterpret_cast<const s16x8*>(Bs + (wn * 64 + n * 16 + lrow) * 32 + lk8 * 8);
#pragma unroll
        for (int m = 0; m < 4; ++m)
#pragma unroll
            for (int n = 0; n < 4; ++n)
                acc[m][n] = __builtin_amdgcn_mfma_f32_16x16x32_bf16(af[m], bfr[n], acc[m][n], 0, 0, 0);
    };

    // prologue: both buffers in flight (8 outstanding vmem ops/wave)
    stage(0, 0);
    stage(1, 32);
    int cur = 0;
    // main loop over tiles 0..NT-2: counted waits, no vmcnt(0) drain
    for (int kt = 0; kt < K - 32; kt += 32) {
        asm volatile("s_waitcnt vmcnt(4)" ::: "memory");  // oldest tile landed
        __builtin_amdgcn_sched_barrier(0);
        __builtin_amdgcn_s_barrier();                     // tile visible to all
        compute(cur);
        __builtin_amdgcn_s_barrier();                     // all reads consumed
        if (kt + 64 < K) stage(cur, kt + 64);             // refill freed buffer
        cur ^= 1;
    }
    // last tile
    asm volatile("s_waitcnt vmcnt(0)" ::: "memory");
    __builtin_amdgcn_sched_barrier(0);
    __builtin_amdgcn_s_barrier();
    compute(cur);
    __syncthreads();                         // full drain before smem reuse

    if constexpr (EPI <= 1) {
        bf16* Cs = (bf16*)smem_raw;          // [128][128]
#pragma unroll
        for (int m = 0; m < 4; ++m)
#pragma unroll
            for (int n = 0; n < 4; ++n) {
                int col = wn * 64 + n * 16 + lrow;
                float bv = bias[nt + col];
#pragma unroll
                for (int j = 0; j < 4; ++j) {
                    int row = wm * 64 + m * 16 + lk8 * 4 + j;
                    float v = acc[m][n][j] + bv;
                    if constexpr (EPI == 1) v = v / (1.0f + __expf(-v));
                    Cs[row * 128 + col] = __float2bfloat16(v);
                }
            }
        __syncthreads();
#pragma unroll
        for (int p = 0; p < 8; ++p) {
            int e = p * 256 + tid;
            int row = e >> 4, ch = (e & 15) * 8;
            *reinterpret_cast<s16x8*>(outB + (size_t)(mrow0 + row) * N + nt + ch) =
                *reinterpret_cast<const s16x8*>(Cs + row * 128 + ch);
        }
    } else {
        float* Cs2 = (float*)smem_raw;       // [64][132] fp32
        const int b = mrow0 / Mspat;
        const int mloc0 = mrow0 - b * Mspat;
        for (int half = 0; half < 2; ++half) {
            if (half) __syncthreads();
            if (wn == half) {
#pragma unroll
                for (int m = 0; m < 4; ++m)
#pragma unroll
                    for (int n = 0; n < 4; ++n) {
                        int crow = n * 16 + lrow;
                        float bv = bias[nt + half * 64 + crow];
#pragma unroll
                        for (int j = 0; j < 4; ++j) {
                            int mcol = wm * 64 + m * 16 + lk8 * 4 + j;
                            Cs2[crow * 132 + mcol] = acc[m][n][j] + bv;
                        }
                    }
            }
            __syncthreads();
#pragma unroll
            for (int p = 0; p < 8; ++p) {
                int e = p * 256 + tid;
                int crow = e >> 5, m4 = (e & 31) * 4;
                int c = nt + half * 64 + crow;
                size_t off = ((size_t)b * C_ + c) * Mspat + mloc0 + m4;
                float4 v  = *reinterpret_cast<const float4*>(Cs2 + crow * 132 + m4);
                float4 q4 = *reinterpret_cast<const float4*>(query + off);
                float s1 = sc1[c];
                float4 o;
                if constexpr (EPI == 2) {
                    o.x = q4.x + v.x * s1;
                    o.y = q4.y + v.y * s1;
                    o.z = q4.z + v.z * s1;
                    o.w = q4.w + v.w * s1;
                } else {
                    float4 w4 = *reinterpret_cast<const float4*>(outF + off);
                    float s2 = sc2[c];
                    o.x = q4.x + (w4.x + v.x * s1) * s2;
                    o.y = q4.y + (w4.y + v.y * s1) * s2;
                    o.z = q4.z + (w4.z + v.z * s1) * s2;
                    o.w = q4.w + (w4.w + v.w * s1) * s2;
                }
                *reinterpret_cast<float4*>(outF + off) = o;
            }
        }
    }
}

// ---------------------------------------------------------------------------
// LayerNorm(384) + elu+1 over bf16 token-major rows, in place. 1 wave/row.
// ---------------------------------------------------------------------------
__global__ __launch_bounds__(256)
void ln_elu_b(bf16* __restrict__ x, const float* __restrict__ w,
              const float* __restrict__ bb)
{
    int lane = threadIdx.x & 63, wid = threadIdx.x >> 6;
    int row = blockIdx.x * 4 + wid;
    bf16* p = x + (size_t)row * C_;
    float v[6];
#pragma unroll
    for (int i = 0; i < 6; ++i) v[i] = __bfloat162float(p[lane + i * 64]);
    float s = 0.0f;
#pragma unroll
    for (int i = 0; i < 6; ++i) s += v[i];
    for (int m = 32; m; m >>= 1) s += __shfl_xor(s, m);
    float mu = s / (float)C_;
    float vs = 0.0f;
#pragma unroll
    for (int i = 0; i < 6; ++i) { float d = v[i] - mu; vs += d * d; }
    for (int m = 32; m; m >>= 1) vs += __shfl_xor(vs, m);
    float inv = rsqrtf(vs / (float)C_ + 1e-5f);
#pragma unroll
    for (int i = 0; i < 6; ++i) {
        int c = lane + i * 64;
        float y = (v[i] - mu) * inv * w[c] + bb[c];
        p[c] = __float2bfloat16((y > 0.0f) ? (y + 1.0f) : __expf(y));
    }
}

// ---------------------------------------------------------------------------
// kv_sum[b,h,d,e] = sum_n k[b,n,h,d]*v[b,n,h,e] ; k_sum[b,h,d] = sum_n k
// ---------------------------------------------------------------------------
__global__ __launch_bounds__(256)
void kv_reduce(const bf16* __restrict__ kn, const bf16* __restrict__ vn,
               float* __restrict__ kv, float* __restrict__ ksum)
{
    const int h = blockIdx.x, b = blockIdx.y;
    __shared__ float Ks[128][48];
    __shared__ float Vs[128][48];
    const int t = threadIdx.x;
    const int d0 = (t >> 4) * 3, e0 = (t & 15) * 3;
    float acc[3][3] = {};
    float ks[3] = {};
    for (int n0 = 0; n0 < NK; n0 += 128) {
        for (int ch = t; ch < 768; ch += 256) {          // 128 rows x 6 chunks
            int r = ch / 6, cc = (ch % 6) * 8;
            size_t base = ((size_t)(b * NK + n0 + r)) * C_ + h * HD + cc;
            s16x8 k8 = *reinterpret_cast<const s16x8*>(kn + base);
            s16x8 v8 = *reinterpret_cast<const s16x8*>(vn + base);
#pragma unroll
            for (int j = 0; j < 8; ++j) {
                Ks[r][cc + j] = bits2f(k8[j]);
                Vs[r][cc + j] = bits2f(v8[j]);
            }
        }
        __syncthreads();
#pragma unroll 4
        for (int r = 0; r < 128; ++r) {
            float k0 = Ks[r][d0], k1 = Ks[r][d0 + 1], k2 = Ks[r][d0 + 2];
            float v0 = Vs[r][e0], v1 = Vs[r][e0 + 1], v2 = Vs[r][e0 + 2];
            acc[0][0] = fmaf(k0, v0, acc[0][0]);
            acc[0][1] = fmaf(k0, v1, acc[0][1]);
            acc[0][2] = fmaf(k0, v2, acc[0][2]);
            acc[1][0] = fmaf(k1, v0, acc[1][0]);
            acc[1][1] = fmaf(k1, v1, acc[1][1]);
            acc[1][2] = fmaf(k1, v2, acc[1][2]);
            acc[2][0] = fmaf(k2, v0, acc[2][0]);
            acc[2][1] = fmaf(k2, v1, acc[2][1]);
            acc[2][2] = fmaf(k2, v2, acc[2][2]);
            if (e0 == 0) { ks[0] += k0; ks[1] += k1; ks[2] += k2; }
        }
        __syncthreads();
    }
    size_t base = (size_t)(b * NH + h) * HD;
#pragma unroll
    for (int i = 0; i < 3; ++i)
#pragma unroll
        for (int j = 0; j < 3; ++j)
            kv[(base + d0 + i) * HD + e0 + j] = acc[i][j];
    if (e0 == 0) {
#pragma unroll
        for (int i = 0; i < 3; ++i) ksum[base + d0 + i] = ks[i];
    }
}

// ---------------------------------------------------------------------------
// attn[b,n,h*48+e] = (sum_d q*kv) / (q.ksum + 1e-8), token-major bf16 out.
// ---------------------------------------------------------------------------
__global__ __launch_bounds__(64)
void attn_numden(const bf16* __restrict__ q, const float* __restrict__ kv,
                 const float* __restrict__ ksum, bf16* __restrict__ attn)
{
    const int nc = blockIdx.x, h = blockIdx.y, b = blockIdx.z;
    __shared__ float skv[48 * 48];
    __shared__ float kss[48];
    const int t = threadIdx.x;
    const float* kvp = kv + (size_t)(b * NH + h) * HD * HD;
    for (int i = t; i < HD * HD; i += 64) skv[i] = kvp[i];
    if (t < HD) kss[t] = ksum[(size_t)(b * NH + h) * HD + t];
    __syncthreads();

    const int n = nc * 64 + t;
    const bf16* qp = q + ((size_t)b * NQ + n) * C_ + h * HD;
    float qv[48];
#pragma unroll
    for (int i = 0; i < 6; ++i) {
        s16x8 v = *reinterpret_cast<const s16x8*>(qp + i * 8);
#pragma unroll
        for (int j = 0; j < 8; ++j) qv[i * 8 + j] = bits2f(v[j]);
    }
    float num[48] = {};
    float den = 0.0f;
#pragma unroll 4
    for (int d = 0; d < 48; ++d) {
        float qd = qv[d];
        den = fmaf(qd, kss[d], den);
#pragma unroll
        for (int e = 0; e < 48; ++e) num[e] = fmaf(qd, skv[d * 48 + e], num[e]);
    }
    float inv = 1.0f / (den + 1e-8f);
    bf16* ap = attn + ((size_t)b * NQ + n) * C_ + h * HD;
#pragma unroll
    for (int i = 0; i < 6; ++i) {
        s16x8 o;
#pragma unroll
        for (int j = 0; j < 8; ++j) o[j] = f2bits(num[i * 8 + j] * inv);
        *reinterpret_cast<s16x8*>(ap + i * 8) = o;
    }
}

// ---------------------------------------------------------------------------
extern "C" void kernel_launch(void* const* d_in, const int* in_sizes, int n_in,
                              void* d_out, int out_size, void* d_ws, size_t ws_size,
                              hipStream_t stream)
{
    const float* query       = (const float*)d_in[0];
    const float* key         = (const float*)d_in[1];
    const float* value       = (const float*)d_in[2];
    const float* ada_gamma   = (const float*)d_in[3];
    const float* ada_beta    = (const float*)d_in[4];
    const float* Wq          = (const float*)d_in[5];
    const float* bq          = (const float*)d_in[6];
    const float* Wk          = (const float*)d_in[7];
    const float* bk          = (const float*)d_in[8];
    const float* Wv          = (const float*)d_in[9];
    const float* bv          = (const float*)d_in[10];
    const float* Wo          = (const float*)d_in[11];
    const float* bo          = (const float*)d_in[12];
    const float* lnq_w       = (const float*)d_in[13];
    const float* lnq_b       = (const float*)d_in[14];
    const float* lnk_w       = (const float*)d_in[15];
    const float* lnk_b       = (const float*)d_in[16];
    const float* attn_scalar = (const float*)d_in[17];
    const float* ffn_gamma   = (const float*)d_in[18];
    const float* ffn_beta    = (const float*)d_in[19];
    const float* W1          = (const float*)d_in[20];
    const float* b1          = (const float*)d_in[21];
    const float* W2          = (const float*)d_in[22];
    const float* b2          = (const float*)d_in[23];
    const float* ffn_scalar  = (const float*)d_in[24];
    const float* final_scalar= (const float*)d_in[25];
    float* out = (float*)d_out;

    // ---- workspace layout (float offsets); peak ~130 MB ----
    float* ws    = (float*)d_ws;
    bf16* qbuf   = (bf16*)(ws);                    // 12.58M bf16 (6.29M fl)
    bf16* attnb  = (bf16*)(ws + 6291456);          // 12.58M bf16
    bf16* kbuf   = (bf16*)(ws + 12582912);         // 3.15M bf16
    bf16* vbuf   = (bf16*)(ws + 14155776);
    bf16* Akb    = (bf16*)(ws + 15728640);
    bf16* Avb    = (bf16*)(ws + 17301504);
    bf16* Aqb    = (bf16*)(ws + 18874368);         // 12.58M bf16
    bf16* hbuf   = (bf16*)(ws);                    // 50.33M bf16 overlay [0,25165824)
    bf16* Awb    = (bf16*)(ws + 25165824);         // 12.58M bf16
    bf16* wqb    = (bf16*)(ws + 31457280);
    bf16* wkb    = wqb + 147456;
    bf16* wvb    = wkb + 147456;
    bf16* wob    = wvb + 147456;
    bf16* w1b    = wob + 147456;
    bf16* w2b    = w1b + 589824;                   // weights end: +884736 fl
    float* kvbuf = ws + 32342016;                  // 147456 fl
    float* ksbuf = kvbuf + 147456;
    float* gx1   = ksbuf + 3072;
    float* sc1b  = gx1 + 3072;
    float* gx2   = sc1b + 3072;
    float* sc2b  = gx2 + 3072;
    // workbuf (`working`, channel-major fp32) lives in d_out.

    // 0. weights -> bf16
    cvt_bf16<<<72, 256, 0, stream>>>(Wq, wqb, 147456);
    cvt_bf16<<<72, 256, 0, stream>>>(Wk, wkb, 147456);
    cvt_bf16<<<72, 256, 0, stream>>>(Wv, wvb, 147456);
    cvt_bf16<<<72, 256, 0, stream>>>(Wo, wob, 147456);
    cvt_bf16<<<288, 256, 0, stream>>>(W1, w1b, 589824);
    cvt_bf16<<<288, 256, 0, stream>>>(W2, w2b, 589824);

    // 1. GRN(query) scale
    grn_gx<<<B_ * C_, 256, 0, stream>>>(query, gx1, NQ);
    grn_scale<<<B_, 384, 0, stream>>>(gx1, ada_gamma, sc1b);

    // 2. transposed bf16 A-matrices (GRN fused for q)
    t2b<true ><<<dim3(64, 6, B_), 256, 0, stream>>>(query, Aqb, sc1b, ada_beta, NQ);
    t2b<false><<<dim3(16, 6, B_), 256, 0, stream>>>(key,   Akb, nullptr, nullptr, NK);
    t2b<false><<<dim3(16, 6, B_), 256, 0, stream>>>(value, Avb, nullptr, nullptr, NK);

    // 3. Q/K/V projections (MFMA, bf16 token-major out)
    gemm_mfma<0><<<dim3(256, 3), 256, 0, stream>>>(Aqb, wqb, bq, 384, 384, NQ,
        qbuf, nullptr, nullptr, nullptr, nullptr);
    gemm_mfma<0><<<dim3(64, 3), 256, 0, stream>>>(Akb, wkb, bk, 384, 384, NK,
        kbuf, nullptr, nullptr, nullptr, nullptr);
    gemm_mfma<0><<<dim3(64, 3), 256, 0, stream>>>(Avb, wvb, bv, 384, 384, NK,
        vbuf, nullptr, nullptr, nullptr, nullptr);

    // 4. LN + elu+1 in place
    ln_elu_b<<<8192, 256, 0, stream>>>(qbuf, lnq_w, lnq_b);
    ln_elu_b<<<2048, 256, 0, stream>>>(kbuf, lnk_w, lnk_b);

    // 5. kv_sum / k_sum and linear attention
    kv_reduce<<<dim3(NH, B_), 256, 0, stream>>>(kbuf, vbuf, kvbuf, ksbuf);
    attn_numden<<<dim3(NQ / 64, NH, B_), 64, 0, stream>>>(qbuf, kvbuf, ksbuf, attnb);

    // 6. Wo projection + residual -> working (channel-major fp32, in d_out)
    gemm_mfma<2><<<dim3(256, 3), 256, 0, stream>>>(attnb, wob, bo, 384, 384, NQ,
        nullptr, out, query, attn_scalar, nullptr);

    // 7. GRN(working) -> Aw (bf16 token-major)
    grn_gx<<<B_ * C_, 256, 0, stream>>>(out, gx2, NQ);
    grn_scale<<<B_, 384, 0, stream>>>(gx2, ffn_gamma, sc2b);
    t2b<true><<<dim3(64, 6, B_), 256, 0, stream>>>(out, Awb, sc2b, ffn_beta, NQ);

    // 8. FFN W1 + silu -> h (bf16 token-major)
    gemm_mfma<1><<<dim3(256, 12), 256, 0, stream>>>(Awb, w1b, b1, 1536, 384, NQ,
        hbuf, nullptr, nullptr, nullptr, nullptr);

    // 9. FFN W2 + residuals -> out (channel-major fp32)
    gemm_mfma<3><<<dim3(256, 3), 256, 0, stream>>>(hbuf, w2b, b2, 384, 1536, NQ,
        nullptr, out, query, ffn_scalar, final_scalar);
}